// Round 1
// baseline (122.522 us; speedup 1.0000x reference)
//
#include <hip/hip_runtime.h>

#define N_Q     40000
#define N_S     40000
#define KK      32
#define PP      15
#define IN_DIM  64
#define OUT_DIM 128

// Kernel 1: valid[s] = (sum_d x[s,d] > 0).  16 lanes per row, coalesced float4.
__global__ __launch_bounds__(256) void rowsum_valid_kernel(
    const float* __restrict__ x, int* __restrict__ valid) {
  int t = blockIdx.x * 256 + threadIdx.x;
  int row = t >> 4;   // 16 lanes per row
  int sub = t & 15;
  if (row >= N_S) return;
  float4 v = reinterpret_cast<const float4*>(x + (size_t)row * IN_DIM)[sub];
  float s = (v.x + v.y) + (v.z + v.w);
  s += __shfl_xor(s, 1, 64);
  s += __shfl_xor(s, 2, 64);
  s += __shfl_xor(s, 4, 64);
  s += __shfl_xor(s, 8, 64);
  if (sub == 0) valid[row] = (s > 0.0f) ? 1 : 0;
}

// Kernel 2: one wave (64 lanes) per query, 4 waves per block.
__global__ __launch_bounds__(256) void kpconv_kernel(
    const float* __restrict__ q_pts, const float* __restrict__ s_pts,
    const int* __restrict__ nidx, const float* __restrict__ x,
    const float* __restrict__ weights, const float* __restrict__ kpts,
    const int* __restrict__ valid, float* __restrict__ out) {
  __shared__ float s_wf[4][PP * IN_DIM];   // 15.4 KB: per-wave weighted features
  __shared__ float s_nbr[4][KK * 3];       // stride-3 packing -> conflict-free
  __shared__ int   s_idx[4][KK];
  __shared__ int   s_pmask[4];
  __shared__ float s_kp[PP * 3];

  const int wave = threadIdx.x >> 6;
  const int lane = threadIdx.x & 63;
  const int n = blockIdx.x * 4 + wave;   // grid is exactly N_Q/4

  if (threadIdx.x < PP * 3) s_kp[threadIdx.x] = kpts[threadIdx.x];
  float* wf = s_wf[wave];
  for (int i = lane; i < PP * IN_DIM; i += 64) wf[i] = 0.0f;
  if (lane == 0) s_pmask[wave] = 0;

  const float qx = q_pts[n * 3 + 0];
  const float qy = q_pts[n * 3 + 1];
  const float qz = q_pts[n * 3 + 2];

  int cnt = 0;
  if (lane < KK) {
    int id = nidx[(size_t)n * KK + lane];
    s_idx[wave][lane] = id;
    float sx = 0.f, sy = 0.f, sz = 0.f;
    if (id < N_S) {   // id == N_S is the shadow row = origin, zero features
      sx = s_pts[id * 3 + 0];
      sy = s_pts[id * 3 + 1];
      sz = s_pts[id * 3 + 2];
      cnt = valid[id];
    }
    s_nbr[wave][lane * 3 + 0] = sx - qx;
    s_nbr[wave][lane * 3 + 1] = sy - qy;
    s_nbr[wave][lane * 3 + 2] = sz - qz;
  }
  unsigned long long bal = __ballot(cnt);
  int num = (int)__popcll(bal);
  if (num < 1) num = 1;
  const float fnum = (float)num;

  __syncthreads();

  // Phase A: evaluate all K*P = 480 kernel-point weights; scatter rare nonzeros.
  for (int i = lane; i < PP * KK; i += 64) {
    const int p = i >> 5;
    const int k = i & 31;
    const float dx = s_nbr[wave][k * 3 + 0] - s_kp[p * 3 + 0];
    const float dy = s_nbr[wave][k * 3 + 1] - s_kp[p * 3 + 1];
    const float dz = s_nbr[wave][k * 3 + 2] - s_kp[p * 3 + 2];
    const float d2 = dx * dx + dy * dy + dz * dz;
    const float w = 1.0f - sqrtf(d2) * 20.0f;   // 1/KP_EXTENT = 20
    const int id = s_idx[wave][k];
    if (w > 0.0f && id < N_S) {                  // shadow features are zero
      atomicOr(&s_pmask[wave], 1 << p);
      const float4* f = reinterpret_cast<const float4*>(x + (size_t)id * IN_DIM);
      float* dst = wf + p * IN_DIM;
      #pragma unroll 4
      for (int d4 = 0; d4 < IN_DIM / 4; ++d4) {
        float4 v = f[d4];
        atomicAdd(&dst[d4 * 4 + 0], w * v.x);
        atomicAdd(&dst[d4 * 4 + 1], w * v.y);
        atomicAdd(&dst[d4 * 4 + 2], w * v.z);
        atomicAdd(&dst[d4 * 4 + 3], w * v.w);
      }
    }
  }
  __syncthreads();

  // Phase B: out[n, :] = sum over active p of wf[p] @ weights[p]; /= num.
  float acc0 = 0.f, acc1 = 0.f;
  int pmask = s_pmask[wave];
  const int o = lane * 2;
  while (pmask) {
    const int p = __ffs(pmask) - 1;
    pmask &= pmask - 1;
    const float* wp = weights + (size_t)p * IN_DIM * OUT_DIM + o;
    const float* wfp = wf + p * IN_DIM;
    #pragma unroll 8
    for (int d = 0; d < IN_DIM; ++d) {
      const float c = wfp[d];                               // LDS broadcast
      const float2 w2 = *reinterpret_cast<const float2*>(wp + (size_t)d * OUT_DIM);
      acc0 += c * w2.x;
      acc1 += c * w2.y;
    }
  }
  float2 res;
  res.x = acc0 / fnum;
  res.y = acc1 / fnum;
  *reinterpret_cast<float2*>(out + (size_t)n * OUT_DIM + o) = res;
}

extern "C" void kernel_launch(void* const* d_in, const int* in_sizes, int n_in,
                              void* d_out, int out_size, void* d_ws, size_t ws_size,
                              hipStream_t stream) {
  const float* q_pts   = (const float*)d_in[0];
  const float* s_pts   = (const float*)d_in[1];
  const int*   nidx    = (const int*)d_in[2];
  const float* x       = (const float*)d_in[3];
  const float* weights = (const float*)d_in[4];
  const float* kpts    = (const float*)d_in[5];
  float* out = (float*)d_out;
  int* valid = (int*)d_ws;   // N_S ints = 160 KB scratch

  rowsum_valid_kernel<<<(N_S * 16) / 256, 256, 0, stream>>>(x, valid);
  kpconv_kernel<<<N_Q / 4, 256, 0, stream>>>(q_pts, s_pts, nidx, x, weights,
                                             kpts, valid, out);
}

// Round 2
// 120.428 us; speedup vs baseline: 1.0174x; 1.0174x over previous
//
#include <hip/hip_runtime.h>

#define N_Q     40000
#define N_S     40000
#define KK      32
#define PP      15
#define IN_DIM  64
#define OUT_DIM 128

// Kernel 1: valid[s] = (sum_d x[s,d] > 0).  16 lanes per row, coalesced float4.
__global__ __launch_bounds__(256) void rowsum_valid_kernel(
    const float* __restrict__ x, int* __restrict__ valid) {
  int t = blockIdx.x * 256 + threadIdx.x;
  int row = t >> 4;   // 16 lanes per row
  int sub = t & 15;
  if (row >= N_S) return;
  float4 v = reinterpret_cast<const float4*>(x + (size_t)row * IN_DIM)[sub];
  float s = (v.x + v.y) + (v.z + v.w);
  s += __shfl_xor(s, 1, 64);
  s += __shfl_xor(s, 2, 64);
  s += __shfl_xor(s, 4, 64);
  s += __shfl_xor(s, 8, 64);
  if (sub == 0) valid[row] = (s > 0.0f) ? 1 : 0;
}

// Kernel 2: one thread per (query, neighbor). No LDS, no barriers.
// Lanes 0-31 of a wave = query 2m, lanes 32-63 = query 2m+1.
// Rare hits (d2 < r^2) are work-shared across the whole wave via ballot+shfl;
// all entries of a query live in one wave, so atomics are uncontended.
__global__ __launch_bounds__(256) void kpconv_kernel(
    const float* __restrict__ q_pts, const float* __restrict__ s_pts,
    const int* __restrict__ nidx, const float* __restrict__ x,
    const float* __restrict__ weights, const float* __restrict__ kpts,
    const int* __restrict__ valid, float* __restrict__ out) {
  const int tid  = blockIdx.x * 256 + threadIdx.x;
  const int lane = threadIdx.x & 63;
  const int n = tid >> 5;        // query index (2 per wave)
  const int k = tid & 31;        // neighbor slot
  (void)k;

  const int id = nidx[tid];      // coalesced: tid == n*KK + k

  float ox = 0.f, oy = 0.f, oz = 0.f;
  int v = 0;
  if (id < N_S) {                // id == N_S: shadow row at origin, zero feats
    ox = s_pts[id * 3 + 0];
    oy = s_pts[id * 3 + 1];
    oz = s_pts[id * 3 + 2];
    v  = valid[id];
  }
  // center on query (broadcast loads within each half-wave; L1 hits)
  ox -= q_pts[n * 3 + 0];
  oy -= q_pts[n * 3 + 1];
  oz -= q_pts[n * 3 + 2];

  // neighbor_num per query: popcount of my half of the ballot
  unsigned long long bal = __ballot(v);
  unsigned int half = (lane < 32) ? (unsigned int)bal
                                  : (unsigned int)(bal >> 32);
  int num = (int)__popc(half);
  if (num < 1) num = 1;
  const float invnum = 1.0f / (float)num;

  const bool real = (id < N_S);

  for (int p = 0; p < PP; ++p) {
    const float dx = ox - kpts[p * 3 + 0];
    const float dy = oy - kpts[p * 3 + 1];
    const float dz = oz - kpts[p * 3 + 2];
    const float d2 = dx * dx + dy * dy + dz * dz;
    const bool hit = real && (d2 < 0.0025f);   // w>0 <=> sqrt(d2) < 0.05
    unsigned long long b2 = __ballot(hit);
    if (b2 == 0ull) continue;                   // wave-uniform skip (common)

    // weight, pre-scaled by 1/num (only executed when wave has a hit)
    const float wn = hit ? (1.0f - 20.0f * sqrtf(d2)) * invnum : 0.0f;

    while (b2) {
      const int j = __ffsll((unsigned long long)b2) - 1;
      b2 &= b2 - 1;
      const float wj  = __shfl(wn, j);
      const int   idj = __shfl(id, j);
      const int   nj  = __shfl(n,  j);

      // whole wave computes w * x[idj] @ W[p]; lane handles 2 output cols
      const float xv = x[(size_t)idj * IN_DIM + lane];   // coalesced 256B
      const float* wp = weights + (size_t)p * IN_DIM * OUT_DIM + 2 * lane;
      float a0 = 0.f, a1 = 0.f;
      #pragma unroll 16
      for (int d = 0; d < IN_DIM; ++d) {
        const float xd = __shfl(xv, d);
        const float2 w2 = *reinterpret_cast<const float2*>(wp + (size_t)d * OUT_DIM);
        a0 += xd * w2.x;
        a1 += xd * w2.y;
      }
      atomicAdd(&out[(size_t)nj * OUT_DIM + 2 * lane + 0], wj * a0);
      atomicAdd(&out[(size_t)nj * OUT_DIM + 2 * lane + 1], wj * a1);
    }
  }
}

extern "C" void kernel_launch(void* const* d_in, const int* in_sizes, int n_in,
                              void* d_out, int out_size, void* d_ws, size_t ws_size,
                              hipStream_t stream) {
  const float* q_pts   = (const float*)d_in[0];
  const float* s_pts   = (const float*)d_in[1];
  const int*   nidx    = (const int*)d_in[2];
  const float* x       = (const float*)d_in[3];
  const float* weights = (const float*)d_in[4];
  const float* kpts    = (const float*)d_in[5];
  float* out = (float*)d_out;
  int* valid = (int*)d_ws;   // N_S ints = 160 KB scratch

  hipMemsetAsync(out, 0, (size_t)out_size * sizeof(float), stream);
  rowsum_valid_kernel<<<(N_S * 16) / 256, 256, 0, stream>>>(x, valid);
  kpconv_kernel<<<(N_Q * KK) / 256, 256, 0, stream>>>(
      q_pts, s_pts, nidx, x, weights, kpts, valid, out);
}